// Round 4
// baseline (213.653 us; speedup 1.0000x reference)
//
#include <hip/hip_runtime.h>
#include <hip/hip_bf16.h>
#include <stdint.h>

#define N_ROWS 16384
#define K_DIM  1024
#define N_OUT  4096

typedef __attribute__((ext_vector_type(8))) short short8;
typedef __attribute__((ext_vector_type(4))) float f32x4;
typedef __attribute__((ext_vector_type(4))) __bf16 bf16x4;

// ---------------- fp32 -> bf16 convert ----------------------------------------
__global__ void cvt_kernel(const float* __restrict__ in, __bf16* __restrict__ out, int n4) {
    int stride = gridDim.x * blockDim.x;
    for (int i = blockIdx.x * blockDim.x + threadIdx.x; i < n4; i += stride) {
        float4 v = reinterpret_cast<const float4*>(in)[i];
        bf16x4 o;
        o[0] = (__bf16)v.x; o[1] = (__bf16)v.y; o[2] = (__bf16)v.z; o[3] = (__bf16)v.w;
        reinterpret_cast<bf16x4*>(out)[i] = o;
    }
}

// ---------------- mask compaction: idx (active rows), zidx (masked), count ----
__global__ __launch_bounds__(256) void scan_kernel(const int* __restrict__ amask,
                                                   int* __restrict__ idx,
                                                   int* __restrict__ zidx,
                                                   int* __restrict__ count) {
    __shared__ int sc[256];
    const int t = threadIdx.x;
    const int base = t * 64;                 // each thread owns 64 contiguous rows
    int c = 0;
    for (int i = 0; i < 64; ++i) c += (amask[base + i] != 0) ? 1 : 0;
    int v = c;
    sc[t] = v;
    __syncthreads();
    for (int off = 1; off < 256; off <<= 1) {   // Hillis-Steele inclusive scan
        int u = (t >= off) ? sc[t - off] : 0;
        __syncthreads();
        v += u; sc[t] = v;
        __syncthreads();
    }
    int b  = v - c;                          // active rows before my range
    int zb = base - (v - c);                 // masked rows before my range
    for (int i = 0; i < 64; ++i) {
        int r = base + i;
        if (amask[r] != 0) idx[b++] = r; else zidx[zb++] = r;
    }
    if (t == 255) count[0] = v;              // total active
}

// ---------------- compacted 256x256-tile pipelined bf16 MFMA GEMM -------------
// Quad-buffered LDS (128 KB), stage kt+3 during kt, ONE s_barrier + vmcnt(4)
// per K-tile. Register-dbuf fragments: P1 reads af[4..7] under MFMA cluster1;
// P2 prefetches kt+1 frags (from already-complete buffer) under cluster2.
// vmcnt LEDGER (4 loads per K-tile, in-order retirement):
//   invariant: end of KT(kt) has vmcnt(4) -> loads through kt+2 landed,
//   only kt+3 outstanding; after the barrier every wave may read buf[kt+1].
//   PROLOGUE must establish this for KT(0): 12 loads in flight (kt0,1,2),
//   wait vmcnt(4) -> kt0 AND kt1 landed (R3 bug: vmcnt(8) only landed kt0).
// Inactive row-tile blocks zero-fill the masked rows instead.

#define GLL(SRC, DSTOFF)                                                       \
    __builtin_amdgcn_global_load_lds(                                          \
        (const __attribute__((address_space(1))) void*)(SRC),                  \
        (__attribute__((address_space(3))) void*)(ldsc + (DSTOFF)), 16, 0, 0)

#define GLLA(sb, kt_) do {                                                     \
    GLL(pA0 + (size_t)(kt_) * 32, (sb)*32768 + t*16);                          \
    GLL(pA1 + (size_t)(kt_) * 32, (sb)*32768 + 8192 + t*16); } while (0)
#define GLLB(sb, kt_) do {                                                     \
    GLL(pB0 + (size_t)(kt_) * 32, (sb)*32768 + 16384 + t*16);                  \
    GLL(pB1 + (size_t)(kt_) * 32, (sb)*32768 + 16384 + 8192 + t*16); } while (0)

// One K-tile. bc=cur buf, sb=stage buf, CA/CB cur frag sets, NA/NB next sets,
// bn=next buf. All compile-time.
#define KT(bc, sb, CA, CB, NA, NB, bn, DO_ST, stk, DO_PF, VMC, DO_VMC, DO_BAR) \
  {                                                                            \
    const short* aC = lds_all + (bc) * 16384;                                  \
    const short* aN = lds_all + (bn) * 16384;                                  \
    if (DO_ST) GLLA(sb, stk);                                                  \
    _Pragma("unroll") for (int m = 0; m < 4; ++m)                              \
      af2[m] = *(const short8*)(aC + (wm*8 + 4 + m)*512 + l*8);                \
    __builtin_amdgcn_s_setprio(1);                                             \
    _Pragma("unroll") for (int m = 0; m < 4; ++m)                              \
      _Pragma("unroll") for (int n = 0; n < 4; ++n)                            \
        acc[m][n] = __builtin_amdgcn_mfma_f32_16x16x32_bf16(                   \
            CA[m], CB[n], acc[m][n], 0, 0, 0);                                 \
    __builtin_amdgcn_s_setprio(0);                                             \
    if (DO_ST) GLLB(sb, stk);                                                  \
    if (DO_PF) {                                                               \
      _Pragma("unroll") for (int m = 0; m < 4; ++m)                            \
        NA[m] = *(const short8*)(aN + (wm*8 + m)*512 + l*8);                   \
      _Pragma("unroll") for (int n = 0; n < 4; ++n)                            \
        NB[n] = *(const short8*)(aN + 8192 + (wn*4 + n)*512 + l*8);            \
    }                                                                          \
    __builtin_amdgcn_s_setprio(1);                                             \
    _Pragma("unroll") for (int m = 0; m < 4; ++m)                              \
      _Pragma("unroll") for (int n = 0; n < 4; ++n)                            \
        acc[4 + m][n] = __builtin_amdgcn_mfma_f32_16x16x32_bf16(               \
            af2[m], CB[n], acc[4 + m][n], 0, 0, 0);                            \
    __builtin_amdgcn_s_setprio(0);                                             \
    if (DO_VMC) asm volatile("s_waitcnt vmcnt(" VMC ")" ::: "memory");         \
    if (DO_BAR) __builtin_amdgcn_s_barrier();                                  \
  }

__global__ __launch_bounds__(512, 2) void gemm_kernel(
    const __bf16* __restrict__ A,
    const __bf16* __restrict__ B,
    const float*  __restrict__ bias,
    const int*    __restrict__ idx,
    const int*    __restrict__ zidx,
    const int*    __restrict__ count,
    float*        __restrict__ out)
{
    __shared__ short lds_all[65536];   // 128 KB: 4 bufs x (A 16KB + B 16KB)

    const int t  = threadIdx.x;
    const int l  = t & 63;
    const int w  = t >> 6;
    const int wm = w >> 2;             // 0..1
    const int wn = w & 3;              // 0..3

    // XCD swizzle with tm as the FAST axis so active row-tiles spread evenly
    // across all 8 XCDs for any active count. Each XCD owns 2 tn columns.
    const int bid = blockIdx.x;
    const int xcd = bid & 7;
    const int c   = bid >> 3;          // 0..127
    const int tn  = xcd * 2 + (c >> 6);
    const int tm  = c & 63;
    const int n0  = tn * 256;

    const int cnt = count[0];
    const int aT  = (cnt + 255) >> 8;  // active row-tiles

    if (tm >= aT) {
        // ---- zero-fill role: clear masked rows for this tn column ----
        const int nz = N_ROWS - cnt;
        const int zt = 64 - aT;        // >= 1 here
        const int z  = tm - aT;
        const int rpz = (nz + zt - 1) / zt;
        const int lo = z * rpz;
        const int hi0 = lo + rpz;
        const int hi = hi0 < nz ? hi0 : nz;
        const float4 zf = make_float4(0.f, 0.f, 0.f, 0.f);
        for (int i = lo + w; i < hi; i += 8) {
            const int row = zidx[i];
            float4* p = reinterpret_cast<float4*>(out + (size_t)row * N_OUT + n0);
            p[l] = zf;                 // 64 lanes x 16B = full 256-col stripe
        }
        return;
    }

    const int m0 = tm * 256;

    // Gathered A staging bases (compile-once per thread); clamp padded slots.
    const int rA  = (w << 4) + (t & 15);
    const int kg8 = ((t >> 4) & 3) * 8;
    const int s0 = m0 + rA, s1 = m0 + rA + 128;
    const int row0 = (s0 < cnt) ? idx[s0] : 0;
    const int row1 = (s1 < cnt) ? idx[s1] : 0;
    const __bf16* pA0 = A + (size_t)row0 * K_DIM + kg8;
    const __bf16* pA1 = A + (size_t)row1 * K_DIM + kg8;
    const __bf16* pB0 = B + (size_t)(n0 + rA) * K_DIM + kg8;
    const __bf16* pB1 = pB0 + (size_t)128 * K_DIM;
    char* ldsc = (char*)lds_all;

    f32x4 acc[8][4] = {};
    short8 afA[4], bfA[4], afB[4], bfB[4], af2[4];

    // Prologue: stage kt0,1,2 (12 loads); vmcnt(4) -> kt0 AND kt1 landed,
    // kt2 (4 newest) still in flight. Establishes the loop invariant.
    GLLA(0, 0); GLLB(0, 0);
    GLLA(1, 1); GLLB(1, 1);
    GLLA(2, 2); GLLB(2, 2);
    asm volatile("s_waitcnt vmcnt(4)" ::: "memory");
    __builtin_amdgcn_s_barrier();
    {
        const short* aC = lds_all;
#pragma unroll
        for (int m = 0; m < 4; ++m) afA[m] = *(const short8*)(aC + (wm*8 + m)*512 + l*8);
#pragma unroll
        for (int n = 0; n < 4; ++n) bfA[n] = *(const short8*)(aC + 8192 + (wn*4 + n)*512 + l*8);
    }

#pragma unroll 1
    for (int j = 0; j < 7; ++j) {              // kt = 4j .. 4j+3 (0..27)
        const int kt = j * 4;
        KT(0, 3, afA, bfA, afB, bfB, 1, 1, kt + 3, 1, "4", 1, 1)
        KT(1, 0, afB, bfB, afA, bfA, 2, 1, kt + 4, 1, "4", 1, 1)
        KT(2, 1, afA, bfA, afB, bfB, 3, 1, kt + 5, 1, "4", 1, 1)
        KT(3, 2, afB, bfB, afA, bfA, 0, 1, kt + 6, 1, "4", 1, 1)
    }
    KT(0, 3, afA, bfA, afB, bfB, 1, 1, 31, 1, "4", 1, 1)   // kt=28, stage 31
    KT(1, 0, afB, bfB, afA, bfA, 2, 0, 0,  1, "0", 1, 1)   // kt=29, drain
    KT(2, 1, afA, bfA, afB, bfB, 3, 0, 0,  1, "0", 0, 1)   // kt=30
    KT(3, 2, afB, bfB, afA, bfA, 0, 0, 0,  0, "0", 0, 0)   // kt=31

    // Epilogue: bias add, scatter to original rows, guard padded slots.
    const int lr = l & 15;
    const int lq = l >> 4;
    float bv[4];
#pragma unroll
    for (int n = 0; n < 4; ++n) bv[n] = bias[n0 + wn*64 + n*16 + lr];

#pragma unroll
    for (int m = 0; m < 8; ++m) {
        const int slot0 = m0 + wm*128 + m*16 + lq*4;
        int rowid[4]; bool val[4];
#pragma unroll
        for (int r = 0; r < 4; ++r) {
            const int s = slot0 + r;
            val[r] = (s < cnt);
            rowid[r] = val[r] ? idx[s] : 0;
        }
#pragma unroll
        for (int n = 0; n < 4; ++n) {
            const int cc = n0 + wn*64 + n*16 + lr;
#pragma unroll
            for (int r = 0; r < 4; ++r)
                if (val[r]) out[(size_t)rowid[r] * N_OUT + cc] = acc[m][n][r] + bv[n];
        }
    }
}

// ---------------- naive fp32 fallback (only if ws too small) ------------------
__global__ void naive_kernel(const float* __restrict__ x, const float* __restrict__ W,
                             const float* __restrict__ bias, const int* __restrict__ amask,
                             float* __restrict__ out) {
    int c = blockIdx.x * blockDim.x + threadIdx.x;
    int r = blockIdx.y;
    if (c >= N_OUT) return;
    if (amask[r] == 0) { out[(size_t)r * N_OUT + c] = 0.0f; return; }
    const float* xr = x + (size_t)r * K_DIM;
    const float* wr = W + (size_t)c * K_DIM;
    float s = 0.0f;
    for (int k = 0; k < K_DIM; ++k) s += xr[k] * wr[k];
    out[(size_t)r * N_OUT + c] = s + bias[c];
}

extern "C" void kernel_launch(void* const* d_in, const int* in_sizes, int n_in,
                              void* d_out, int out_size, void* d_ws, size_t ws_size,
                              hipStream_t stream) {
    const float* x     = (const float*)d_in[0];
    const int*   amask = (const int*)d_in[1];
    const float* W     = (const float*)d_in[2];
    const float* bias  = (const float*)d_in[3];
    float*       out   = (float*)d_out;

    const size_t xb_bytes = (size_t)N_ROWS * K_DIM * 2;   // 32 MB
    const size_t wb_bytes = (size_t)N_OUT  * K_DIM * 2;   //  8 MB
    const size_t idx_bytes = (size_t)N_ROWS * 4;          // 64 KB
    const size_t need = xb_bytes + wb_bytes + 2 * idx_bytes + 256;

    if (ws_size < need) {
        dim3 g((N_OUT + 255) / 256, N_ROWS);
        naive_kernel<<<g, 256, 0, stream>>>(x, W, bias, amask, out);
        return;
    }

    __bf16* xb   = (__bf16*)d_ws;
    __bf16* wb   = (__bf16*)((char*)d_ws + xb_bytes);
    int*    idx  = (int*)((char*)d_ws + xb_bytes + wb_bytes);
    int*    zidx = idx + N_ROWS;
    int*    cnt  = zidx + N_ROWS;

    scan_kernel<<<1, 256, 0, stream>>>(amask, idx, zidx, cnt);
    cvt_kernel<<<2048, 256, 0, stream>>>(x, xb, N_ROWS * K_DIM / 4);
    cvt_kernel<<<1024, 256, 0, stream>>>(W, wb, N_OUT * K_DIM / 4);

    gemm_kernel<<<1024, 512, 0, stream>>>(xb, wb, bias, idx, zidx, cnt, out);
}

// Round 5
// 190.684 us; speedup vs baseline: 1.1205x; 1.1205x over previous
//
#include <hip/hip_runtime.h>
#include <hip/hip_bf16.h>
#include <stdint.h>

#define N_ROWS 16384
#define K_DIM  1024
#define N_OUT  4096

typedef __attribute__((ext_vector_type(8))) short short8;
typedef __attribute__((ext_vector_type(4))) float f32x4;
typedef __attribute__((ext_vector_type(4))) __bf16 bf16x4;

// ---------------- fp32 -> bf16 convert (dense, for W) -------------------------
__global__ void cvt_kernel(const float* __restrict__ in, __bf16* __restrict__ out, int n4) {
    int stride = gridDim.x * blockDim.x;
    for (int i = blockIdx.x * blockDim.x + threadIdx.x; i < n4; i += stride) {
        float4 v = reinterpret_cast<const float4*>(in)[i];
        bf16x4 o;
        o[0] = (__bf16)v.x; o[1] = (__bf16)v.y; o[2] = (__bf16)v.z; o[3] = (__bf16)v.w;
        reinterpret_cast<bf16x4*>(out)[i] = o;
    }
}

// ---------------- gather + convert: xb[i] = bf16(x[idx[i]]), i < cnt ----------
// Compacts active rows so the GEMM reads dense contiguous A panels.
__global__ __launch_bounds__(256) void cvt_gather_kernel(
    const float* __restrict__ x, const int* __restrict__ idx,
    const int* __restrict__ count, __bf16* __restrict__ xb) {
    const int cnt = count[0];
    const int t = threadIdx.x;                   // 256 threads = 256 float4/row
    for (int j = blockIdx.x; j < cnt; j += gridDim.x) {
        const int row = idx[j];
        float4 v = reinterpret_cast<const float4*>(x + (size_t)row * K_DIM)[t];
        bf16x4 o;
        o[0] = (__bf16)v.x; o[1] = (__bf16)v.y; o[2] = (__bf16)v.z; o[3] = (__bf16)v.w;
        reinterpret_cast<bf16x4*>(xb + (size_t)j * K_DIM)[t] = o;
    }
}

// ---------------- mask compaction: idx (active rows), zidx (masked), count ----
__global__ __launch_bounds__(1024) void scan_kernel(const int* __restrict__ amask,
                                                    int* __restrict__ idx,
                                                    int* __restrict__ zidx,
                                                    int* __restrict__ count) {
    __shared__ int sc[1024];
    const int t = threadIdx.x;
    const int base = t * 16;                     // 16 rows per thread
    int mk[16];
#pragma unroll
    for (int g = 0; g < 4; ++g) {
        int4 m4 = reinterpret_cast<const int4*>(amask + base)[g];
        mk[g*4+0] = m4.x; mk[g*4+1] = m4.y; mk[g*4+2] = m4.z; mk[g*4+3] = m4.w;
    }
    int c = 0;
#pragma unroll
    for (int i = 0; i < 16; ++i) c += (mk[i] != 0) ? 1 : 0;
    int v = c;
    sc[t] = v;
    __syncthreads();
    for (int off = 1; off < 1024; off <<= 1) {   // Hillis-Steele inclusive scan
        int u = (t >= off) ? sc[t - off] : 0;
        __syncthreads();
        v += u; sc[t] = v;
        __syncthreads();
    }
    int b  = v - c;                              // active rows before my range
    int zb = base - b;                           // masked rows before my range
#pragma unroll
    for (int i = 0; i < 16; ++i) {
        int r = base + i;
        if (mk[i] != 0) idx[b++] = r; else zidx[zb++] = r;
    }
    if (t == 1023) count[0] = v;                 // total active
}

// ---------------- compacted 256x256-tile pipelined bf16 MFMA GEMM -------------
// A = compacted active rows (dense). Quad-buffered LDS (128 KB), stage kt+3
// during kt, ONE s_barrier + counted vmcnt(4) per K-tile, reg-dbuf fragments.
// vmcnt LEDGER: end of KT(kt) waits vmcnt(4) -> loads through kt+2 landed,
// only kt+3 outstanding. Prologue: stage kt0,1,2 then vmcnt(4) (kt0+kt1 land).
// XCD-chunked mapping: q=ceil(aT/8) heavy row-tiles per XCD (A set ~2MB,
// L2-resident), tm local-fast; trivial slots re-ranked to zero-fill blocks.

#define GLL(SRC, DSTOFF)                                                       \
    __builtin_amdgcn_global_load_lds(                                          \
        (const __attribute__((address_space(1))) void*)(SRC),                  \
        (__attribute__((address_space(3))) void*)(ldsc + (DSTOFF)), 16, 0, 0)

#define GLLA(sb, kt_) do {                                                     \
    GLL(pA0 + (size_t)(kt_) * 32, (sb)*32768 + t*16);                          \
    GLL(pA1 + (size_t)(kt_) * 32, (sb)*32768 + 8192 + t*16); } while (0)
#define GLLB(sb, kt_) do {                                                     \
    GLL(pB0 + (size_t)(kt_) * 32, (sb)*32768 + 16384 + t*16);                  \
    GLL(pB1 + (size_t)(kt_) * 32, (sb)*32768 + 16384 + 8192 + t*16); } while (0)

#define KT(bc, sb, CA, CB, NA, NB, bn, DO_ST, stk, DO_PF, VMC, DO_VMC, DO_BAR) \
  {                                                                            \
    const short* aC = lds_all + (bc) * 16384;                                  \
    const short* aN = lds_all + (bn) * 16384;                                  \
    if (DO_ST) GLLA(sb, stk);                                                  \
    _Pragma("unroll") for (int m = 0; m < 4; ++m)                              \
      af2[m] = *(const short8*)(aC + (wm*8 + 4 + m)*512 + l*8);                \
    __builtin_amdgcn_s_setprio(1);                                             \
    _Pragma("unroll") for (int m = 0; m < 4; ++m)                              \
      _Pragma("unroll") for (int n = 0; n < 4; ++n)                            \
        acc[m][n] = __builtin_amdgcn_mfma_f32_16x16x32_bf16(                   \
            CA[m], CB[n], acc[m][n], 0, 0, 0);                                 \
    __builtin_amdgcn_s_setprio(0);                                             \
    if (DO_ST) GLLB(sb, stk);                                                  \
    if (DO_PF) {                                                               \
      _Pragma("unroll") for (int m = 0; m < 4; ++m)                            \
        NA[m] = *(const short8*)(aN + (wm*8 + m)*512 + l*8);                   \
      _Pragma("unroll") for (int n = 0; n < 4; ++n)                            \
        NB[n] = *(const short8*)(aN + 8192 + (wn*4 + n)*512 + l*8);            \
    }                                                                          \
    __builtin_amdgcn_s_setprio(1);                                             \
    _Pragma("unroll") for (int m = 0; m < 4; ++m)                              \
      _Pragma("unroll") for (int n = 0; n < 4; ++n)                            \
        acc[4 + m][n] = __builtin_amdgcn_mfma_f32_16x16x32_bf16(               \
            af2[m], CB[n], acc[4 + m][n], 0, 0, 0);                            \
    __builtin_amdgcn_s_setprio(0);                                             \
    if (DO_VMC) asm volatile("s_waitcnt vmcnt(" VMC ")" ::: "memory");         \
    if (DO_BAR) __builtin_amdgcn_s_barrier();                                  \
  }

__global__ __launch_bounds__(512, 2) void gemm_kernel(
    const __bf16* __restrict__ A,      // compacted active rows
    const __bf16* __restrict__ B,
    const float*  __restrict__ bias,
    const int*    __restrict__ idx,
    const int*    __restrict__ zidx,
    const int*    __restrict__ count,
    float*        __restrict__ out)
{
    __shared__ short lds_all[65536];   // 128 KB: 4 bufs x (A 16KB + B 16KB)

    const int t  = threadIdx.x;
    const int l  = t & 63;
    const int w  = t >> 6;
    const int wm = w >> 2;             // 0..1
    const int wn = w & 3;              // 0..3

    const int cnt = count[0];
    const int aT  = (cnt + 255) >> 8;  // active row-tiles (0..64)
    const int q   = (aT + 7) >> 3;     // heavy tm per XCD (ceil)

    const int bid = blockIdx.x;
    const int xcd = bid & 7;
    const int c   = bid >> 3;          // 0..127
    const int pre = min(xcd * q, aT);  // heavy tiles owned by XCDs before us
    int own = aT - pre; if (own > q) own = q; if (own < 0) own = 0;

    if (c >= own * 16) {
        // ---- zero-fill role: trivial rank -> (tn column, zero-row slice) ----
        const int tr  = (128 * xcd - 16 * pre) + (c - 16 * own);
        const int tnt = tr & 15;
        const int zsl = tr >> 4;           // 0 .. (64-aT-1)
        const int zt  = 64 - aT;           // >=1 whenever trivial blocks exist
        const int nz  = N_ROWS - cnt;
        const int rpz = (nz + zt - 1) / zt;
        const int lo  = zsl * rpz;
        const int hi0 = lo + rpz;
        const int hi  = hi0 < nz ? hi0 : nz;
        const int n0z = tnt * 256;
        const float4 zf = make_float4(0.f, 0.f, 0.f, 0.f);
        for (int i = lo + w; i < hi; i += 8) {
            const int row = zidx[i];
            float4* p = reinterpret_cast<float4*>(out + (size_t)row * N_OUT + n0z);
            p[l] = zf;                     // 64 lanes x 16B = full 256-col stripe
        }
        return;
    }

    // ---- heavy role: tm local-fast within this XCD's contiguous chunk ----
    const int tm = pre + (c % own);
    const int tn = c / own;
    const int m0 = tm * 256;               // slot base in COMPACTED space
    const int n0 = tn * 256;

    const int rA  = (w << 4) + (t & 15);
    const int kg8 = ((t >> 4) & 3) * 8;
    const __bf16* pA0 = A + (size_t)(m0 + rA) * K_DIM + kg8;   // dense panels
    const __bf16* pA1 = pA0 + (size_t)128 * K_DIM;
    const __bf16* pB0 = B + (size_t)(n0 + rA) * K_DIM + kg8;
    const __bf16* pB1 = pB0 + (size_t)128 * K_DIM;
    char* ldsc = (char*)lds_all;

    f32x4 acc[8][4] = {};
    short8 afA[4], bfA[4], afB[4], bfB[4], af2[4];

    // Prologue: stage kt0,1,2 (12 loads); vmcnt(4) -> kt0 AND kt1 landed.
    GLLA(0, 0); GLLB(0, 0);
    GLLA(1, 1); GLLB(1, 1);
    GLLA(2, 2); GLLB(2, 2);
    asm volatile("s_waitcnt vmcnt(4)" ::: "memory");
    __builtin_amdgcn_s_barrier();
    {
        const short* aC = lds_all;
#pragma unroll
        for (int m = 0; m < 4; ++m) afA[m] = *(const short8*)(aC + (wm*8 + m)*512 + l*8);
#pragma unroll
        for (int n = 0; n < 4; ++n) bfA[n] = *(const short8*)(aC + 8192 + (wn*4 + n)*512 + l*8);
    }

#pragma unroll 1
    for (int j = 0; j < 7; ++j) {              // kt = 4j .. 4j+3 (0..27)
        const int kt = j * 4;
        KT(0, 3, afA, bfA, afB, bfB, 1, 1, kt + 3, 1, "4", 1, 1)
        KT(1, 0, afB, bfB, afA, bfA, 2, 1, kt + 4, 1, "4", 1, 1)
        KT(2, 1, afA, bfA, afB, bfB, 3, 1, kt + 5, 1, "4", 1, 1)
        KT(3, 2, afB, bfB, afA, bfA, 0, 1, kt + 6, 1, "4", 1, 1)
    }
    KT(0, 3, afA, bfA, afB, bfB, 1, 1, 31, 1, "4", 1, 1)   // kt=28, stage 31
    KT(1, 0, afB, bfB, afA, bfA, 2, 0, 0,  1, "0", 1, 1)   // kt=29, drain
    KT(2, 1, afA, bfA, afB, bfB, 3, 0, 0,  1, "0", 0, 1)   // kt=30
    KT(3, 2, afB, bfB, afA, bfA, 0, 0, 0,  0, "0", 0, 0)   // kt=31

    // Epilogue: bias add, scatter to original rows, guard padded slots.
    const int lr = l & 15;
    const int lq = l >> 4;
    float bv[4];
#pragma unroll
    for (int n = 0; n < 4; ++n) bv[n] = bias[n0 + wn*64 + n*16 + lr];

#pragma unroll
    for (int m = 0; m < 8; ++m) {
        const int slot0 = m0 + wm*128 + m*16 + lq*4;
        int rowid[4]; bool val[4];
#pragma unroll
        for (int r = 0; r < 4; ++r) {
            const int s = slot0 + r;
            val[r] = (s < cnt);
            rowid[r] = val[r] ? idx[s] : 0;
        }
#pragma unroll
        for (int n = 0; n < 4; ++n) {
            const int cc = n0 + wn*64 + n*16 + lr;
#pragma unroll
            for (int r = 0; r < 4; ++r)
                if (val[r]) out[(size_t)rowid[r] * N_OUT + cc] = acc[m][n][r] + bv[n];
        }
    }
}

// ---------------- naive fp32 fallback (only if ws too small) ------------------
__global__ void naive_kernel(const float* __restrict__ x, const float* __restrict__ W,
                             const float* __restrict__ bias, const int* __restrict__ amask,
                             float* __restrict__ out) {
    int c = blockIdx.x * blockDim.x + threadIdx.x;
    int r = blockIdx.y;
    if (c >= N_OUT) return;
    if (amask[r] == 0) { out[(size_t)r * N_OUT + c] = 0.0f; return; }
    const float* xr = x + (size_t)r * K_DIM;
    const float* wr = W + (size_t)c * K_DIM;
    float s = 0.0f;
    for (int k = 0; k < K_DIM; ++k) s += xr[k] * wr[k];
    out[(size_t)r * N_OUT + c] = s + bias[c];
}

extern "C" void kernel_launch(void* const* d_in, const int* in_sizes, int n_in,
                              void* d_out, int out_size, void* d_ws, size_t ws_size,
                              hipStream_t stream) {
    const float* x     = (const float*)d_in[0];
    const int*   amask = (const int*)d_in[1];
    const float* W     = (const float*)d_in[2];
    const float* bias  = (const float*)d_in[3];
    float*       out   = (float*)d_out;

    const size_t xb_bytes = (size_t)N_ROWS * K_DIM * 2;   // 32 MB (full alloc)
    const size_t wb_bytes = (size_t)N_OUT  * K_DIM * 2;   //  8 MB
    const size_t idx_bytes = (size_t)N_ROWS * 4;          // 64 KB
    const size_t need = xb_bytes + wb_bytes + 2 * idx_bytes + 256;

    if (ws_size < need) {
        dim3 g((N_OUT + 255) / 256, N_ROWS);
        naive_kernel<<<g, 256, 0, stream>>>(x, W, bias, amask, out);
        return;
    }

    __bf16* xb   = (__bf16*)d_ws;
    __bf16* wb   = (__bf16*)((char*)d_ws + xb_bytes);
    int*    idx  = (int*)((char*)d_ws + xb_bytes + wb_bytes);
    int*    zidx = idx + N_ROWS;
    int*    cnt  = zidx + N_ROWS;

    scan_kernel<<<1, 1024, 0, stream>>>(amask, idx, zidx, cnt);
    cvt_gather_kernel<<<2048, 256, 0, stream>>>(x, idx, cnt, xb);
    cvt_kernel<<<1024, 256, 0, stream>>>(W, wb, N_OUT * K_DIM / 4);

    gemm_kernel<<<1024, 512, 0, stream>>>(xb, wb, bias, idx, zidx, cnt, out);
}

// Round 6
// 189.364 us; speedup vs baseline: 1.1283x; 1.0070x over previous
//
#include <hip/hip_runtime.h>
#include <hip/hip_bf16.h>
#include <stdint.h>

#define N_ROWS 16384
#define K_DIM  1024
#define N_OUT  4096

typedef __attribute__((ext_vector_type(8))) short short8;
typedef __attribute__((ext_vector_type(4))) float f32x4;
typedef __attribute__((ext_vector_type(4))) __bf16 bf16x4;

// ---------------- fp32 -> bf16 convert (dense, for W) -------------------------
__global__ void cvt_kernel(const float* __restrict__ in, __bf16* __restrict__ out, int n4) {
    int stride = gridDim.x * blockDim.x;
    for (int i = blockIdx.x * blockDim.x + threadIdx.x; i < n4; i += stride) {
        float4 v = reinterpret_cast<const float4*>(in)[i];
        bf16x4 o;
        o[0] = (__bf16)v.x; o[1] = (__bf16)v.y; o[2] = (__bf16)v.z; o[3] = (__bf16)v.w;
        reinterpret_cast<bf16x4*>(out)[i] = o;
    }
}

// ---------------- gather + convert: xb[i] = bf16(x[idx[i]]), i < cnt ----------
__global__ __launch_bounds__(256) void cvt_gather_kernel(
    const float* __restrict__ x, const int* __restrict__ idx,
    const int* __restrict__ count, __bf16* __restrict__ xb) {
    const int cnt = count[0];
    const int t = threadIdx.x;                   // 256 threads = 256 float4/row
    for (int j = blockIdx.x; j < cnt; j += gridDim.x) {
        const int row = idx[j];
        float4 v = reinterpret_cast<const float4*>(x + (size_t)row * K_DIM)[t];
        bf16x4 o;
        o[0] = (__bf16)v.x; o[1] = (__bf16)v.y; o[2] = (__bf16)v.z; o[3] = (__bf16)v.w;
        reinterpret_cast<bf16x4*>(xb + (size_t)j * K_DIM)[t] = o;
    }
}

// ---------------- mask compaction: idx (active rows), zidx (masked), count ----
__global__ __launch_bounds__(1024) void scan_kernel(const int* __restrict__ amask,
                                                    int* __restrict__ idx,
                                                    int* __restrict__ zidx,
                                                    int* __restrict__ count) {
    __shared__ int sc[1024];
    const int t = threadIdx.x;
    const int base = t * 16;                     // 16 rows per thread
    int mk[16];
#pragma unroll
    for (int g = 0; g < 4; ++g) {
        int4 m4 = reinterpret_cast<const int4*>(amask + base)[g];
        mk[g*4+0] = m4.x; mk[g*4+1] = m4.y; mk[g*4+2] = m4.z; mk[g*4+3] = m4.w;
    }
    int c = 0;
#pragma unroll
    for (int i = 0; i < 16; ++i) c += (mk[i] != 0) ? 1 : 0;
    int v = c;
    sc[t] = v;
    __syncthreads();
    for (int off = 1; off < 1024; off <<= 1) {   // Hillis-Steele inclusive scan
        int u = (t >= off) ? sc[t - off] : 0;
        __syncthreads();
        v += u; sc[t] = v;
        __syncthreads();
    }
    int b  = v - c;
    int zb = base - b;
#pragma unroll
    for (int i = 0; i < 16; ++i) {
        int r = base + i;
        if (mk[i] != 0) idx[b++] = r; else zidx[zb++] = r;
    }
    if (t == 1023) count[0] = v;
}

// ---------------- 8-phase 256x256 bf16 MFMA GEMM (m201 template port) ---------
// BK=64 split as two K-halves (kh/ks = 0,1) of 32. LDS: 2 bufs x 64KB,
// slots per buf: A-kh0 @0, A-kh1 @16KB, B-kh0 @32KB, B-kh1 @48KB (frag-linear:
// frag f at f*1KB, lane l at l*16B -> ds_read_b128 lane-consecutive, 0 confl).
// Window k (4 phases, buf BC=k&1): phase i: ks=i>>1, mh=i&1;
//   ds: i=0: a(m0-3,ks0)+b(ks0)=8 reads; i=1: a(m4-7,ks0)=4; i=2: 8; i=3: 4.
//   stage: i=0: A-kh1(k+1)->BC^1; i=1: B-kh0(k+2)->BC; i=2: A-kh0(k+2)->BC;
//          i=3: B-kh1(k+2)->BC, then vmcnt(6) (3 half-tiles in flight), barrier.
// Ledger: gate at end of window k covers stages <= tick 4k (A-kh1(k+1));
//   every slot's first read is after its covering gate; every stage targets a
//   slot whose old data was last read >=1 phase earlier (barrier between).
// Prologue: B0h0,A0h0,B0h1,A0h1 vmcnt(4); B1h0,A1h0,B1h1 vmcnt(6); barrier.
// Tail: window 14 stages only A-kh1(15), gate vmcnt(0); window 15 stages none.

#define GLL(SRC, DSTOFF)                                                       \
    __builtin_amdgcn_global_load_lds(                                          \
        (const __attribute__((address_space(1))) void*)(SRC),                  \
        (__attribute__((address_space(3))) void*)(ldsc + (DSTOFF)), 16, 0, 0)

#define STG_A(b, kh, kt) do {                                                  \
    GLL(pA0 + (size_t)(kt)*64 + (kh)*32, (b)*65536 + (kh)*16384 + t*16);       \
    GLL(pA1 + (size_t)(kt)*64 + (kh)*32, (b)*65536 + (kh)*16384 + 8192 + t*16);\
  } while (0)
#define STG_B(b, kh, kt) do {                                                  \
    GLL(pB0 + (size_t)(kt)*64 + (kh)*32, (b)*65536 + 32768 + (kh)*16384 + t*16);\
    GLL(pB1 + (size_t)(kt)*64 + (kh)*32, (b)*65536 + 32768 + (kh)*16384 + 8192 + t*16);\
  } while (0)

#define GATE6 asm volatile("s_waitcnt vmcnt(6)" ::: "memory")
#define GATE0 asm volatile("s_waitcnt vmcnt(0)" ::: "memory")
#define NOSTG ((void)0)

// One phase. BUFC/KS/MH/LDB compile-time. STG = staging stmt, GATE = vmcnt.
#define PHASE(BUFC, KS, MH, LDB, STG, GATE)                                    \
  {                                                                            \
    _Pragma("unroll") for (int m = 0; m < 4; ++m)                              \
      aR[MH][m] = *(const short8*)(lds_all + (BUFC)*32768 + (KS)*8192 +        \
                                   (wm*8 + (MH)*4 + m)*512 + l*8);             \
    if (LDB) {                                                                 \
      _Pragma("unroll") for (int n = 0; n < 4; ++n)                            \
        bR[KS][n] = *(const short8*)(lds_all + (BUFC)*32768 + 16384 +          \
                                     (KS)*8192 + (wn*4 + n)*512 + l*8);        \
    }                                                                          \
    STG;                                                                       \
    __builtin_amdgcn_s_barrier();                                              \
    __builtin_amdgcn_s_setprio(1);                                             \
    _Pragma("unroll") for (int m = 0; m < 4; ++m)                              \
      _Pragma("unroll") for (int n = 0; n < 4; ++n)                            \
        acc[(MH)*4 + m][n] = __builtin_amdgcn_mfma_f32_16x16x32_bf16(          \
            aR[MH][m], bR[KS][n], acc[(MH)*4 + m][n], 0, 0, 0);                \
    __builtin_amdgcn_s_setprio(0);                                             \
    GATE;                                                                      \
    __builtin_amdgcn_s_barrier();                                              \
  }

// Full steady window: K-tile KT in buf BC; stages per the ledger above.
#define WINDOW_FULL(BC, KT)                                                    \
  PHASE(BC, 0, 0, 1, STG_A((BC)^1, 1, (KT)+1), NOSTG)                          \
  PHASE(BC, 0, 1, 0, STG_B((BC),   0, (KT)+2), NOSTG)                          \
  PHASE(BC, 1, 0, 1, STG_A((BC),   0, (KT)+2), NOSTG)                          \
  PHASE(BC, 1, 1, 0, STG_B((BC),   1, (KT)+2), GATE6)

__global__ __launch_bounds__(512, 2) void gemm_kernel(
    const __bf16* __restrict__ A,      // compacted active rows
    const __bf16* __restrict__ B,
    const float*  __restrict__ bias,
    const int*    __restrict__ idx,
    const int*    __restrict__ zidx,
    const int*    __restrict__ count,
    float*        __restrict__ out)
{
    __shared__ short lds_all[65536];   // 128 KB: 2 bufs x 64 KB

    const int t  = threadIdx.x;
    const int l  = t & 63;
    const int w  = t >> 6;
    const int wm = w >> 2;             // 0..1 (row half: 128 rows each)
    const int wn = w & 3;              // 0..3 (col quarter: 64 cols each)

    const int cnt = count[0];
    const int aT  = (cnt + 255) >> 8;  // active row-tiles (0..64)
    const int q   = (aT + 7) >> 3;     // heavy tm per XCD (ceil)

    const int bid = blockIdx.x;
    const int xcd = bid & 7;
    const int c   = bid >> 3;          // 0..127
    const int pre = min(xcd * q, aT);
    int own = aT - pre; if (own > q) own = q; if (own < 0) own = 0;

    if (c >= own * 16) {
        // ---- zero-fill role ----
        const int tr  = (128 * xcd - 16 * pre) + (c - 16 * own);
        const int tnt = tr & 15;
        const int zsl = tr >> 4;
        const int zt  = 64 - aT;
        const int nz  = N_ROWS - cnt;
        const int rpz = (nz + zt - 1) / zt;
        const int lo  = zsl * rpz;
        const int hi0 = lo + rpz;
        const int hi  = hi0 < nz ? hi0 : nz;
        const int n0z = tnt * 256;
        const float4 zf = make_float4(0.f, 0.f, 0.f, 0.f);
        for (int i = lo + w; i < hi; i += 8) {
            const int row = zidx[i];
            float4* p = reinterpret_cast<float4*>(out + (size_t)row * N_OUT + n0z);
            p[l] = zf;
        }
        return;
    }

    // ---- heavy role ----
    const int tm = pre + (c % own);
    const int tn = c / own;
    const int m0 = tm * 256;               // base in COMPACTED row space
    const int n0 = tn * 256;

    // Frag-linear staging sources: thread t writes LDS byte t*16 of a half-tile
    // = frag (t>>6), lane (t&63) -> row = frag*16 + (l&15), k-sub = ((t>>4)&3)*8.
    const int rowoff = ((t >> 6) << 4) + (t & 15);
    const int klane  = ((t >> 4) & 3) * 8;
    const __bf16* pA0 = A + (size_t)(m0 + rowoff) * K_DIM + klane;
    const __bf16* pA1 = pA0 + (size_t)128 * K_DIM;
    const __bf16* pB0 = B + (size_t)(n0 + rowoff) * K_DIM + klane;
    const __bf16* pB1 = pB0 + (size_t)128 * K_DIM;
    char* ldsc = (char*)lds_all;

    f32x4 acc[8][4] = {};
    short8 aR[2][4], bR[2][4];

    // Prologue (template-exact): 4 half-tiles, vmcnt(4); +3, vmcnt(6); barrier.
    STG_B(0, 0, 0); STG_A(0, 0, 0); STG_B(0, 1, 0); STG_A(0, 1, 0);
    asm volatile("s_waitcnt vmcnt(4)" ::: "memory");
    STG_B(1, 0, 1); STG_A(1, 0, 1); STG_B(1, 1, 1);
    asm volatile("s_waitcnt vmcnt(6)" ::: "memory");
    __builtin_amdgcn_s_barrier();

#pragma unroll 1
    for (int j = 0; j < 7; ++j) {          // windows k = 0..13
        const int KT2 = 2 * j;
        WINDOW_FULL(0, KT2)
        WINDOW_FULL(1, KT2 + 1)
    }
    // Tail: window 14 (buf0) stages only A-kh1(15); drain gate vmcnt(0).
    PHASE(0, 0, 0, 1, STG_A(1, 1, 15), NOSTG)
    PHASE(0, 0, 1, 0, NOSTG, NOSTG)
    PHASE(0, 1, 0, 1, NOSTG, NOSTG)
    PHASE(0, 1, 1, 0, NOSTG, GATE0)
    // Window 15 (buf1): no stages, no gate.
    PHASE(1, 0, 0, 1, NOSTG, NOSTG)
    PHASE(1, 0, 1, 0, NOSTG, NOSTG)
    PHASE(1, 1, 0, 1, NOSTG, NOSTG)
    PHASE(1, 1, 1, 0, NOSTG, NOSTG)

    // Epilogue: bias add, scatter to original rows, guard padded slots.
    const int lr = l & 15;
    const int lq = l >> 4;
    float bv[4];
#pragma unroll
    for (int n = 0; n < 4; ++n) bv[n] = bias[n0 + wn*64 + n*16 + lr];

#pragma unroll
    for (int m = 0; m < 8; ++m) {
        const int slot0 = m0 + wm*128 + m*16 + lq*4;
        int rowid[4]; bool val[4];
#pragma unroll
        for (int r = 0; r < 4; ++r) {
            const int s = slot0 + r;
            val[r] = (s < cnt);
            rowid[r] = val[r] ? idx[s] : 0;
        }
#pragma unroll
        for (int n = 0; n < 4; ++n) {
            const int cc = n0 + wn*64 + n*16 + lr;
#pragma unroll
            for (int r = 0; r < 4; ++r)
                if (val[r]) out[(size_t)rowid[r] * N_OUT + cc] = acc[m][n][r] + bv[n];
        }
    }
}

// ---------------- naive fp32 fallback (only if ws too small) ------------------
__global__ void naive_kernel(const float* __restrict__ x, const float* __restrict__ W,
                             const float* __restrict__ bias, const int* __restrict__ amask,
                             float* __restrict__ out) {
    int c = blockIdx.x * blockDim.x + threadIdx.x;
    int r = blockIdx.y;
    if (c >= N_OUT) return;
    if (amask[r] == 0) { out[(size_t)r * N_OUT + c] = 0.0f; return; }
    const float* xr = x + (size_t)r * K_DIM;
    const float* wr = W + (size_t)c * K_DIM;
    float s = 0.0f;
    for (int k = 0; k < K_DIM; ++k) s += xr[k] * wr[k];
    out[(size_t)r * N_OUT + c] = s + bias[c];
}

extern "C" void kernel_launch(void* const* d_in, const int* in_sizes, int n_in,
                              void* d_out, int out_size, void* d_ws, size_t ws_size,
                              hipStream_t stream) {
    const float* x     = (const float*)d_in[0];
    const int*   amask = (const int*)d_in[1];
    const float* W     = (const float*)d_in[2];
    const float* bias  = (const float*)d_in[3];
    float*       out   = (float*)d_out;

    const size_t xb_bytes = (size_t)N_ROWS * K_DIM * 2;   // 32 MB
    const size_t wb_bytes = (size_t)N_OUT  * K_DIM * 2;   //  8 MB
    const size_t idx_bytes = (size_t)N_ROWS * 4;          // 64 KB
    const size_t need = xb_bytes + wb_bytes + 2 * idx_bytes + 256;

    if (ws_size < need) {
        dim3 g((N_OUT + 255) / 256, N_ROWS);
        naive_kernel<<<g, 256, 0, stream>>>(x, W, bias, amask, out);
        return;
    }

    __bf16* xb   = (__bf16*)d_ws;
    __bf16* wb   = (__bf16*)((char*)d_ws + xb_bytes);
    int*    idx  = (int*)((char*)d_ws + xb_bytes + wb_bytes);
    int*    zidx = idx + N_ROWS;
    int*    cnt  = zidx + N_ROWS;

    scan_kernel<<<1, 1024, 0, stream>>>(amask, idx, zidx, cnt);
    cvt_gather_kernel<<<2048, 256, 0, stream>>>(x, idx, cnt, xb);
    cvt_kernel<<<1024, 256, 0, stream>>>(W, wb, N_OUT * K_DIM / 4);

    gemm_kernel<<<1024, 512, 0, stream>>>(xb, wb, bias, idx, zidx, cnt, out);
}